// Round 5
// baseline (291.324 us; speedup 1.0000x reference)
//
#include <hip/hip_runtime.h>
#include <hip/hip_bf16.h>

typedef __bf16 bf16x8 __attribute__((ext_vector_type(8)));
typedef float  f32x4  __attribute__((ext_vector_type(4)));

typedef __attribute__((address_space(3))) unsigned int as3_u32;
typedef __attribute__((address_space(1))) unsigned int as1_u32;

__device__ __forceinline__ void gld_lds16(const void* gptr, void* lptr){
  __builtin_amdgcn_global_load_lds((const as1_u32*)gptr, (as3_u32*)lptr, 16, 0, 0);
}

// ---------------- weight convert + transpose: in[R][C] f32 -> out[C][R] bf16
__global__ __launch_bounds__(256) void transpose_cvt(const float* __restrict__ in,
                                                     __bf16* __restrict__ out, int R, int C){
  __shared__ float tile[32][33];
  const int c0 = blockIdx.x*32, r0 = blockIdx.y*32;
  const int tx = threadIdx.x, ty = threadIdx.y;
  #pragma unroll
  for (int i=0;i<32;i+=8)
    tile[ty+i][tx] = in[(size_t)(r0+ty+i)*C + c0+tx];
  __syncthreads();
  #pragma unroll
  for (int i=0;i<32;i+=8)
    out[(size_t)(c0+ty+i)*R + r0+tx] = (__bf16)tile[tx][ty+i];
}

// ---------------- layernorm: rows of 1024 f32 -> bf16
__global__ __launch_bounds__(256) void ln_kernel(const float* __restrict__ x, const float* __restrict__ g,
                                                 const float* __restrict__ b, __bf16* __restrict__ out){
  const int row = blockIdx.x, t = threadIdx.x;
  const float4 v = ((const float4*)(x + (size_t)row*1024))[t];
  float s = v.x+v.y+v.z+v.w;
  #pragma unroll
  for (int m=1;m<64;m<<=1) s += __shfl_xor(s, m);
  __shared__ float red[8];
  if ((t&63)==0) red[t>>6] = s;
  __syncthreads();
  const float mu = (red[0]+red[1]+red[2]+red[3]) * (1.f/1024.f);
  const float d0=v.x-mu, d1=v.y-mu, d2=v.z-mu, d3=v.w-mu;
  float sq = d0*d0+d1*d1+d2*d2+d3*d3;
  #pragma unroll
  for (int m=1;m<64;m<<=1) sq += __shfl_xor(sq, m);
  if ((t&63)==0) red[4+(t>>6)] = sq;
  __syncthreads();
  const float var = (red[4]+red[5]+red[6]+red[7]) * (1.f/1024.f);
  const float inv = rsqrtf(var + 1e-12f);
  const float4 gv = ((const float4*)g)[t];
  const float4 bv = ((const float4*)b)[t];
  union { __bf16 h[4]; uint2 u; } pk;
  pk.h[0]=(__bf16)(d0*inv*gv.x+bv.x); pk.h[1]=(__bf16)(d1*inv*gv.y+bv.y);
  pk.h[2]=(__bf16)(d2*inv*gv.z+bv.z); pk.h[3]=(__bf16)(d3*inv*gv.w+bv.w);
  *(uint2*)(out + (size_t)row*1024 + t*4) = pk.u;
}

// ---------------- GEMM (m97 128x128 structure) for N=1024 shapes
// MODE 1: outF = C + bias + resid (fp32)
template<int MODE>
__global__ __launch_bounds__(256) void gemm_bt(
    const __bf16* __restrict__ A, const __bf16* __restrict__ Bt,
    const float* __restrict__ bias, const float* __restrict__ resid,
    float* __restrict__ outF, int M, int N, int K)
{
  __shared__ __align__(16) __bf16 As[128*32];
  __shared__ __align__(16) __bf16 Bs[128*32];
  const int tid = threadIdx.x;
  const int lane = tid & 63, wave = tid >> 6;
  const int wr = wave >> 1, wc = wave & 1;
  const int l15 = lane & 15, lg = lane >> 4;
  const int bm = blockIdx.x, bn = blockIdx.y;
  const __bf16* Ab = A  + (size_t)bm*128*K;
  const __bf16* Bb = Bt + (size_t)bn*128*K;
  f32x4 acc[4][4] = {};
  const int r0 = tid >> 2;
  const int c0 = (tid & 3) * 8;
  char* lA0 = (char*)As + wave*1024;
  char* lA1 = (char*)As + 4096 + wave*1024;
  char* lB0 = (char*)Bs + wave*1024;
  char* lB1 = (char*)Bs + 4096 + wave*1024;
  const int nk = K >> 5;
  for (int kt = 0; kt < nk; ++kt){
    __syncthreads();
    const int k0 = kt*32;
    gld_lds16(Ab + (size_t)r0*K      + k0 + c0, lA0);
    gld_lds16(Ab + (size_t)(r0+64)*K + k0 + c0, lA1);
    gld_lds16(Bb + (size_t)r0*K      + k0 + c0, lB0);
    gld_lds16(Bb + (size_t)(r0+64)*K + k0 + c0, lB1);
    __syncthreads();
    bf16x8 af[4], bfv[4];
    #pragma unroll
    for (int i=0;i<4;++i){
      af[i]  = *(const bf16x8*)&As[(wr*64 + i*16 + l15)*32 + lg*8];
      bfv[i] = *(const bf16x8*)&Bs[(wc*64 + i*16 + l15)*32 + lg*8];
    }
    #pragma unroll
    for (int i=0;i<4;++i)
      #pragma unroll
      for (int j=0;j<4;++j)
        acc[i][j] = __builtin_amdgcn_mfma_f32_16x16x32_bf16(af[i], bfv[j], acc[i][j], 0,0,0);
  }
  #pragma unroll
  for (int i=0;i<4;++i){
    #pragma unroll
    for (int j=0;j<4;++j){
      const int col = bn*128 + wc*64 + j*16 + l15;
      const float bv = bias[col];
      #pragma unroll
      for (int r=0;r<4;++r){
        const int row = bm*128 + wr*64 + i*16 + lg*4 + r;
        float v = acc[i][j][r] + bv;
        outF[(size_t)row*N + col] = v + resid[(size_t)row*N + col];
      }
    }
  }
}

// ---------------- 8-phase 256x256 GEMM (T3+T4+T5+T1), BK=64, 8 waves (2Mx4N)
// LDS: A,B each [2 buf][2 ks][256 rows][32 k] bf16 (64 B rows -> m97 bank geometry, no swizzle)
// MODE 0: QKV scatter -> Q[bh][s][d], K[bh][s][d], Vt[bh][d][s]
// MODE 2: outB = gelu_exact(C) bf16, no bias
template<int MODE>
__global__ __launch_bounds__(512, 2) void gemm8(
    const __bf16* __restrict__ A, const __bf16* __restrict__ Bt,
    const float* __restrict__ bias, __bf16* __restrict__ outB,
    __bf16* __restrict__ qO, __bf16* __restrict__ kO, __bf16* __restrict__ vtO,
    int nbm, int N, int K)
{
  __shared__ __align__(16) char lds[131072];
  char* lA = lds;
  char* lB = lds + 65536;
  const int tid = threadIdx.x;
  const int lane = tid & 63, wave = tid >> 6;
  const int wm = wave >> 2, wn = wave & 3;
  const int l15 = lane & 15, lg = lane >> 4;
  // T1: XCD-aware swizzle (grid % 8 == 0)
  const int nwg = (int)gridDim.x;
  const int b0  = (int)blockIdx.x;
  const int sw  = (b0 & 7)*(nwg >> 3) + (b0 >> 3);
  const int bm = sw % nbm, bn = sw / nbm;
  const __bf16* Ab = A  + (size_t)bm*256*K;
  const __bf16* Bb = Bt + (size_t)bn*256*K;
  const int nkt = K >> 6, nit = nkt >> 1;
  f32x4 acc[8][4] = {};

  const int srow = wave*32 + (lane>>2);       // stage row (second load: +16)
  const int scol = (lane&3)*8;                // stage col (elems)

  auto stage = [&](int kt, int isB, int ks){
    if (kt >= nkt) return;
    char* dst = (isB ? lB : lA) + (((kt&1)*2 + ks)<<14) + wave*2048;
    const __bf16* src = (isB ? Bb : Ab) + (size_t)srow*K + kt*64 + ks*32 + scol;
    gld_lds16(src, dst);
    gld_lds16(src + (size_t)16*K, dst + 1024);
  };

  bf16x8 aF[4], bF[4];
  auto loadA = [&](int kt, int ks, int mh){
    const char* At = lA + (((kt&1)*2 + ks)<<14);
    #pragma unroll
    for (int m=0;m<4;++m)
      aF[m] = *(const bf16x8*)(At + (wm*128 + mh*64 + m*16 + l15)*64 + lg*16);
  };
  auto loadB = [&](int kt, int ks){
    const char* Bl = lB + (((kt&1)*2 + ks)<<14);
    #pragma unroll
    for (int n=0;n<4;++n)
      bF[n] = *(const bf16x8*)(Bl + (wn*64 + n*16 + l15)*64 + lg*16);
  };
  auto mmac = [&](int mh){
    __builtin_amdgcn_s_setprio(1);
    #pragma unroll
    for (int m=0;m<4;++m)
      #pragma unroll
      for (int n=0;n<4;++n)
        acc[mh*4+m][n] = __builtin_amdgcn_mfma_f32_16x16x32_bf16(aF[m], bF[n], acc[mh*4+m][n], 0,0,0);
    __builtin_amdgcn_s_setprio(0);
  };

  #define BARX() { __builtin_amdgcn_s_barrier(); __builtin_amdgcn_sched_barrier(0); }
  #define LGKM0() { asm volatile("s_waitcnt lgkmcnt(0)" ::: "memory"); __builtin_amdgcn_sched_barrier(0); }
  #define VM4() { asm volatile("s_waitcnt vmcnt(4)" ::: "memory"); __builtin_amdgcn_sched_barrier(0); }
  #define VM0() { asm volatile("s_waitcnt vmcnt(0)" ::: "memory"); __builtin_amdgcn_sched_barrier(0); }

  // prologue: tile0 all 4 parts + tile1 k0 parts (12 loads/wave)
  stage(0,0,0); stage(0,1,0); stage(0,0,1); stage(0,1,1); stage(1,0,0); stage(1,1,0);
  VM4();   // tile0 fully landed (8 completed, 4 outstanding)
  BARX();

  for (int it = 0; it < nit; ++it){
    const int t0 = 2*it, t1 = 2*it+1;
    const bool last = (it == nit-1);
    // p0: compute t0 (ks0, mh0) ; stage t1.A_k1
    loadA(t0,0,0); loadB(t0,0); stage(t1,0,1);
    BARX(); LGKM0(); mmac(0); BARX();
    // p1: (ks0, mh1) ; stage t1.B_k1
    loadA(t0,0,1); stage(t1,1,1);
    BARX(); LGKM0(); mmac(1); BARX();
    // p2: (ks1, mh0) ; stage t0+2.A_k0
    loadA(t0,1,0); loadB(t0,1); stage(t0+2,0,0);
    BARX(); LGKM0(); mmac(0); BARX();
    // p3: (ks1, mh1) ; stage t0+2.B_k0 ; vmcnt boundary
    loadA(t0,1,1); stage(t0+2,1,0);
    BARX(); LGKM0(); mmac(1);
    if (last) { VM0(); } else { VM4(); }
    BARX();
    // p4: compute t1 (ks0, mh0) ; stage t0+2.A_k1
    loadA(t1,0,0); loadB(t1,0); stage(t0+2,0,1);
    BARX(); LGKM0(); mmac(0); BARX();
    // p5: (ks0, mh1) ; stage t0+2.B_k1
    loadA(t1,0,1); stage(t0+2,1,1);
    BARX(); LGKM0(); mmac(1); BARX();
    // p6: (ks1, mh0) ; stage t0+3.A_k0
    loadA(t1,1,0); loadB(t1,1); stage(t0+3,0,0);
    BARX(); LGKM0(); mmac(0); BARX();
    // p7: (ks1, mh1) ; stage t0+3.B_k0 ; vmcnt boundary
    loadA(t1,1,1); stage(t0+3,1,0);
    BARX(); LGKM0(); mmac(1);
    if (!last) { VM4(); }
    BARX();
  }
  #undef BARX
  #undef LGKM0
  #undef VM4
  #undef VM0

  // epilogue
  #pragma unroll
  for (int mi=0;mi<8;++mi){
    #pragma unroll
    for (int n=0;n<4;++n){
      const int col = bn*256 + wn*64 + n*16 + l15;
      float bv;
      if constexpr (MODE==0) bv = bias[col]; else bv = 0.f;
      #pragma unroll
      for (int r=0;r<4;++r){
        const int row = bm*256 + wm*128 + mi*16 + lg*4 + r;
        float v = acc[mi][n][r] + bv;
        if constexpr (MODE==0){
          const int b_ = row >> 11, s_ = row & 2047;
          if (col < 1024){
            const int h = col>>6, d = col&63;
            qO[((size_t)(b_*16+h)*2048 + s_)*64 + d] = (__bf16)v;
          } else if (col < 2048){
            const int h = (col-1024)>>6, d = (col-1024)&63;
            kO[((size_t)(b_*16+h)*2048 + s_)*64 + d] = (__bf16)v;
          } else {
            const int h = (col-2048)>>6, d = (col-2048)&63;
            vtO[((size_t)(b_*16+h)*64 + d)*2048 + s_] = (__bf16)v;
          }
        } else {
          const float gl = 0.5f*v*(1.f + erff(v*0.70710678118f));
          outB[(size_t)row*N + col] = (__bf16)gl;
        }
      }
    }
  }
}

// ---------------- flash attention (round-3 structure, known-good).
// Block: 512 threads / 8 waves, 128 q-rows (16/wave). KVBLK=64, double-buffered LDS,
// stage-before-compute pipeline, swapped QK^T (lane owns one q-row -> in-lane softmax).
__global__ __launch_bounds__(512, 4) void attn_kernel(
    const __bf16* __restrict__ Q, const __bf16* __restrict__ K,
    const __bf16* __restrict__ Vt, __bf16* __restrict__ out)
{
  __shared__ __align__(16) __bf16 Ks[2][64*64];
  __shared__ __align__(16) __bf16 Vs[2][64*64];
  __shared__ __align__(16) __bf16 Pl[8][16*64];
  const int tid = threadIdx.x;
  const int lane = tid & 63, wave = tid >> 6;
  const int l15 = lane & 15, lg = lane >> 4;
  const int bh = blockIdx.y;
  const int qblk = (int)(gridDim.x - 1) - blockIdx.x;   // longest blocks first
  const int qb = qblk * 128;
  const int qw = qb + wave*16;                          // wave's first q-row
  const __bf16* Qh = Q + (size_t)bh*2048*64;
  const char*  Khc = (const char*)(K  + (size_t)bh*2048*64);
  const char*  Vhc = (const char*)(Vt + (size_t)bh*64*2048);

  bf16x8 qf[2];
  #pragma unroll
  for (int f=0;f<2;++f){
    bf16x8 t8 = *(const bf16x8*)&Qh[(size_t)(qw + l15)*64 + f*32 + lg*8];
    #pragma unroll
    for (int j=0;j<8;++j) t8[j] = (__bf16)((float)t8[j] * 0.125f);
    qf[f] = t8;
  }

  f32x4 oacc[4] = {};
  float mrun = -1e30f, lrun = 0.f;

  const int swz_st = (((lane&7) ^ (lane>>3)) << 4);
  const int rswz = ((l15 & 7) << 4);
  const int srow = wave*8 + (lane>>3);
  char* Pw = (char*)&Pl[wave][0];
  char* ldsK[2] = { (char*)&Ks[0][0] + wave*1024, (char*)&Ks[1][0] + wave*1024 };
  char* ldsV[2] = { (char*)&Vs[0][0] + wave*1024, (char*)&Vs[1][0] + wave*1024 };

  const int nst = qblk*2 + 2;

  gld_lds16(Khc + (size_t)srow*128 + swz_st, ldsK[0]);
  gld_lds16(Vhc + (size_t)srow*4096 + swz_st, ldsV[0]);
  __syncthreads();

  for (int st = 0; st < nst; ++st){
    const int cur = st & 1;
    const int kv0 = st*64;
    if (st+1 < nst){
      const size_t nkv0 = (size_t)(kv0 + 64);
      gld_lds16(Khc + (nkv0 + srow)*128 + swz_st, ldsK[cur^1]);
      gld_lds16(Vhc + (size_t)srow*4096 + nkv0*2 + swz_st, ldsV[cur^1]);
    }
    if (kv0 <= qw + 15){
      const char* Kb = (const char*)&Ks[cur][0];
      const char* Vb = (const char*)&Vs[cur][0];
      f32x4 sc[4] = {};
      #pragma unroll
      for (int t=0;t<4;++t){
        const int row = t*16 + l15;
        bf16x8 k0 = *(const bf16x8*)(Kb + row*128 + ((lg*16)      ^ rswz));
        bf16x8 k1 = *(const bf16x8*)(Kb + row*128 + ((64 + lg*16) ^ rswz));
        sc[t] = __builtin_amdgcn_mfma_f32_16x16x32_bf16(k0, qf[0], sc[t], 0,0,0);
        sc[t] = __builtin_amdgcn_mfma_f32_16x16x32_bf16(k1, qf[1], sc[t], 0,0,0);
      }
      if (kv0 + 63 > qw){
        const int q = qw + l15;
        #pragma unroll
        for (int t=0;t<4;++t)
          #pragma unroll
          for (int r=0;r<4;++r)
            if (kv0 + t*16 + lg*4 + r > q) sc[t][r] = -1e30f;
      }
      f32x4 m01, m23;
      #pragma unroll
      for (int r=0;r<4;++r){ m01[r] = fmaxf(sc[0][r], sc[1][r]); m23[r] = fmaxf(sc[2][r], sc[3][r]); }
      float mx = fmaxf(fmaxf(fmaxf(m01[0],m23[0]), fmaxf(m01[1],m23[1])),
                       fmaxf(fmaxf(m01[2],m23[2]), fmaxf(m01[3],m23[3])));
      mx = fmaxf(mx, __shfl_xor(mx, 16));
      mx = fmaxf(mx, __shfl_xor(mx, 32));
      const float nm = fmaxf(mrun, mx);
      const float co = exp2f((mrun - nm) * 1.44269504f);
      #pragma unroll
      for (int t=0;t<4;++t)
        #pragma unroll
        for (int r=0;r<4;++r)
          sc[t][r] = exp2f((sc[t][r] - nm) * 1.44269504f);
      f32x4 s01, s23;
      #pragma unroll
      for (int r=0;r<4;++r){ s01[r] = sc[0][r]+sc[1][r]; s23[r] = sc[2][r]+sc[3][r]; }
      float rs = ((s01[0]+s23[0])+(s01[1]+s23[1])) + ((s01[2]+s23[2])+(s01[3]+s23[3]));
      rs += __shfl_xor(rs, 16);
      rs += __shfl_xor(rs, 32);
      lrun = lrun*co + rs;
      mrun = nm;
      float cor[4];
      #pragma unroll
      for (int r=0;r<4;++r) cor[r] = __shfl(co, lg*4+r);
      #pragma unroll
      for (int c=0;c<4;++c)
        #pragma unroll
        for (int r=0;r<4;++r)
          oacc[c][r] *= cor[r];
      // P -> per-wave swizzled LDS tile, one uint2 (b64) write per t
      #pragma unroll
      for (int t=0;t<4;++t){
        union { __bf16 h[4]; uint2 u; } pk4;
        pk4.h[0] = (__bf16)sc[t][0];
        pk4.h[1] = (__bf16)sc[t][1];
        pk4.h[2] = (__bf16)sc[t][2];
        pk4.h[3] = (__bf16)sc[t][3];
        *(uint2*)(Pw + l15*128 + ((t*32 + lg*8) ^ rswz)) = pk4.u;
      }
      #pragma unroll
      for (int f=0;f<2;++f){
        bf16x8 pa = *(const bf16x8*)(Pw + l15*128 + ((f*64 + lg*16) ^ rswz));
        #pragma unroll
        for (int c=0;c<4;++c){
          bf16x8 vf = *(const bf16x8*)(Vb + (c*16+l15)*128 + ((f*64 + lg*16) ^ rswz));
          oacc[c] = __builtin_amdgcn_mfma_f32_16x16x32_bf16(pa, vf, oacc[c], 0,0,0);
        }
      }
    }
    __syncthreads();
  }

  const int b_ = bh >> 4, h_ = bh & 15;
  float lr[4];
  #pragma unroll
  for (int r=0;r<4;++r) lr[r] = __shfl(lrun, lg*4+r);
  #pragma unroll
  for (int c=0;c<4;++c)
    #pragma unroll
    for (int r=0;r<4;++r){
      const int row = qw + lg*4 + r;
      out[((size_t)(b_*2048 + row))*1024 + h_*64 + c*16 + l15] = (__bf16)(oacc[c][r] / lr[r]);
    }
}

extern "C" void kernel_launch(void* const* d_in, const int* in_sizes, int n_in,
                              void* d_out, int out_size, void* d_ws, size_t ws_size,
                              hipStream_t stream) {
  const float* x      = (const float*)d_in[0];
  const float* ln1_g  = (const float*)d_in[1];
  const float* ln1_b  = (const float*)d_in[2];
  const float* w_qkv  = (const float*)d_in[3];
  const float* b_qkv  = (const float*)d_in[4];
  const float* w_dense= (const float*)d_in[5];
  const float* b_dense= (const float*)d_in[6];
  const float* ln2_g  = (const float*)d_in[7];
  const float* ln2_b  = (const float*)d_in[8];
  const float* w_fc1  = (const float*)d_in[9];
  const float* w_fc2  = (const float*)d_in[10];
  const float* b_fc2  = (const float*)d_in[11];

  char* ws = (char*)d_ws;
  __bf16* wqkvT  = (__bf16*)(ws + 0);          // [3072][1024]  6 MB
  __bf16* wdenT  = (__bf16*)(ws + 6291456);    // [1024][1024]  2 MB
  __bf16* wfc1T  = (__bf16*)(ws + 8388608);    // [2048][1024]  4 MB
  __bf16* wfc2T  = (__bf16*)(ws + 12582912);   // [1024][2048]  4 MB
  __bf16* xn     = (__bf16*)(ws + 16777216);   // [4096][1024]  8 MB
  __bf16* Qb     = (__bf16*)(ws + 25165824);   // [32][2048][64] 8 MB
  __bf16* Kb     = (__bf16*)(ws + 33554432);   // [32][2048][64] 8 MB
  __bf16* Vtb    = (__bf16*)(ws + 41943040);   // [32][64][2048] 8 MB
  __bf16* attnb  = (__bf16*)(ws + 50331648);   // [4096][1024]  8 MB
  float*  outf   = (float*) (ws + 58720256);   // [4096][1024] 16 MB
  __bf16* mb     = (__bf16*)(ws + 75497472);   // [4096][1024]  8 MB
  __bf16* h1b    = (__bf16*)(ws + 83886080);   // [4096][2048] 16 MB

  dim3 blkT(32,8);
  transpose_cvt<<<dim3(3072/32, 1024/32), blkT, 0, stream>>>(w_qkv,   wqkvT, 1024, 3072);
  transpose_cvt<<<dim3(1024/32, 1024/32), blkT, 0, stream>>>(w_dense, wdenT, 1024, 1024);
  transpose_cvt<<<dim3(2048/32, 1024/32), blkT, 0, stream>>>(w_fc1,   wfc1T, 1024, 2048);
  transpose_cvt<<<dim3(1024/32, 2048/32), blkT, 0, stream>>>(w_fc2,   wfc2T, 2048, 1024);
  ln_kernel<<<4096, 256, 0, stream>>>(x, ln1_g, ln1_b, xn);
  // QKV: 8-phase 256^2, grid 16x12 = 192 blocks
  gemm8<0><<<192, 512, 0, stream>>>(xn, wqkvT, b_qkv, nullptr,
                                    Qb, Kb, Vtb, 16, 3072, 1024);
  attn_kernel<<<dim3(16,32), 512, 0, stream>>>(Qb, Kb, Vtb, attnb);
  gemm_bt<1><<<dim3(32,8), 256, 0, stream>>>(attnb, wdenT, b_dense, x,
                                             outf, 4096, 1024, 1024);
  ln_kernel<<<4096, 256, 0, stream>>>(outf, ln2_g, ln2_b, mb);
  // FC1 + GELU: 8-phase 256^2, grid 16x8 = 128 blocks
  gemm8<2><<<128, 512, 0, stream>>>(mb, wfc1T, nullptr, h1b,
                                    nullptr, nullptr, nullptr, 16, 2048, 1024);
  gemm_bt<1><<<dim3(32,8), 256, 0, stream>>>(h1b, wfc2T, b_fc2, outf,
                                             (float*)d_out, 4096, 1024, 2048);
}

// Round 6
// 248.158 us; speedup vs baseline: 1.1739x; 1.1739x over previous
//
#include <hip/hip_runtime.h>
#include <hip/hip_bf16.h>

typedef __bf16 bf16x8 __attribute__((ext_vector_type(8)));
typedef float  f32x4  __attribute__((ext_vector_type(4)));

typedef __attribute__((address_space(3))) unsigned int as3_u32;
typedef __attribute__((address_space(1))) unsigned int as1_u32;

__device__ __forceinline__ void gld_lds16(const void* gptr, void* lptr){
  __builtin_amdgcn_global_load_lds((const as1_u32*)gptr, (as3_u32*)lptr, 16, 0, 0);
}

// ---------------- all-weight convert + transpose: in[R][C] f32 -> out[C][R] bf16 (one launch)
__global__ __launch_bounds__(256) void transpose_all(
    const float* __restrict__ w_qkv, const float* __restrict__ w_dense,
    const float* __restrict__ w_fc1, const float* __restrict__ w_fc2,
    __bf16* __restrict__ oqkv, __bf16* __restrict__ oden,
    __bf16* __restrict__ ofc1, __bf16* __restrict__ ofc2){
  __shared__ float tile[32][33];
  int idx = blockIdx.x;
  const float* in; __bf16* out; int R, C;
  if (idx < 3072){ in = w_qkv;  out = oqkv; R = 1024; C = 3072; }
  else if (idx < 4096){ idx -= 3072; in = w_dense; out = oden; R = 1024; C = 1024; }
  else if (idx < 6144){ idx -= 4096; in = w_fc1;  out = ofc1; R = 1024; C = 2048; }
  else { idx -= 6144; in = w_fc2;  out = ofc2; R = 2048; C = 1024; }
  const int ntx = C >> 5;
  const int c0 = (idx % ntx)*32, r0 = (idx / ntx)*32;
  const int tx = threadIdx.x, ty = threadIdx.y;
  #pragma unroll
  for (int i=0;i<32;i+=8)
    tile[ty+i][tx] = in[(size_t)(r0+ty+i)*C + c0+tx];
  __syncthreads();
  #pragma unroll
  for (int i=0;i<32;i+=8)
    out[(size_t)(c0+ty+i)*R + r0+tx] = (__bf16)tile[tx][ty+i];
}

// ---------------- layernorm: rows of 1024 f32 -> bf16
__global__ __launch_bounds__(256) void ln_kernel(const float* __restrict__ x, const float* __restrict__ g,
                                                 const float* __restrict__ b, __bf16* __restrict__ out){
  const int row = blockIdx.x, t = threadIdx.x;
  const float4 v = ((const float4*)(x + (size_t)row*1024))[t];
  float s = v.x+v.y+v.z+v.w;
  #pragma unroll
  for (int m=1;m<64;m<<=1) s += __shfl_xor(s, m);
  __shared__ float red[8];
  if ((t&63)==0) red[t>>6] = s;
  __syncthreads();
  const float mu = (red[0]+red[1]+red[2]+red[3]) * (1.f/1024.f);
  const float d0=v.x-mu, d1=v.y-mu, d2=v.z-mu, d3=v.w-mu;
  float sq = d0*d0+d1*d1+d2*d2+d3*d3;
  #pragma unroll
  for (int m=1;m<64;m<<=1) sq += __shfl_xor(sq, m);
  if ((t&63)==0) red[4+(t>>6)] = sq;
  __syncthreads();
  const float var = (red[4]+red[5]+red[6]+red[7]) * (1.f/1024.f);
  const float inv = rsqrtf(var + 1e-12f);
  const float4 gv = ((const float4*)g)[t];
  const float4 bv = ((const float4*)b)[t];
  union { __bf16 h[4]; uint2 u; } pk;
  pk.h[0]=(__bf16)(d0*inv*gv.x+bv.x); pk.h[1]=(__bf16)(d1*inv*gv.y+bv.y);
  pk.h[2]=(__bf16)(d2*inv*gv.z+bv.z); pk.h[3]=(__bf16)(d3*inv*gv.w+bv.w);
  *(uint2*)(out + (size_t)row*1024 + t*4) = pk.u;
}

// ---------------- GEMM: C[M,N] = A[M,K](bf16,row) @ Bt[N,K](bf16,row)^T + bias, fused epilogues
// MODE 0: QKV scatter -> Q[bh][s][d], K[bh][s][d], Vt[bh][d][s]  (bf16)
// MODE 1: outF = C + bias + resid (fp32)
// MODE 2: outB = gelu_exact(C) (bf16), no bias
template<int MODE>
__global__ __launch_bounds__(256) void gemm_bt(
    const __bf16* __restrict__ A, const __bf16* __restrict__ Bt,
    const float* __restrict__ bias, const float* __restrict__ resid,
    float* __restrict__ outF, __bf16* __restrict__ outB,
    __bf16* __restrict__ qO, __bf16* __restrict__ kO, __bf16* __restrict__ vtO,
    int M, int N, int K)
{
  __shared__ __align__(16) __bf16 As[128*32];
  __shared__ __align__(16) __bf16 Bs[128*32];
  const int tid = threadIdx.x;
  const int lane = tid & 63, wave = tid >> 6;
  const int wr = wave >> 1, wc = wave & 1;
  const int l15 = lane & 15, lg = lane >> 4;
  const int bm = blockIdx.x, bn = blockIdx.y;
  const __bf16* Ab = A  + (size_t)bm*128*K;
  const __bf16* Bb = Bt + (size_t)bn*128*K;
  f32x4 acc[4][4] = {};
  const int r0 = tid >> 2;
  const int c0 = (tid & 3) * 8;
  char* lA0 = (char*)As + wave*1024;
  char* lA1 = (char*)As + 4096 + wave*1024;
  char* lB0 = (char*)Bs + wave*1024;
  char* lB1 = (char*)Bs + 4096 + wave*1024;
  const int nk = K >> 5;
  for (int kt = 0; kt < nk; ++kt){
    __syncthreads();
    const int k0 = kt*32;
    gld_lds16(Ab + (size_t)r0*K      + k0 + c0, lA0);
    gld_lds16(Ab + (size_t)(r0+64)*K + k0 + c0, lA1);
    gld_lds16(Bb + (size_t)r0*K      + k0 + c0, lB0);
    gld_lds16(Bb + (size_t)(r0+64)*K + k0 + c0, lB1);
    __syncthreads();
    bf16x8 af[4], bfv[4];
    #pragma unroll
    for (int i=0;i<4;++i){
      af[i]  = *(const bf16x8*)&As[(wr*64 + i*16 + l15)*32 + lg*8];
      bfv[i] = *(const bf16x8*)&Bs[(wc*64 + i*16 + l15)*32 + lg*8];
    }
    #pragma unroll
    for (int i=0;i<4;++i)
      #pragma unroll
      for (int j=0;j<4;++j)
        acc[i][j] = __builtin_amdgcn_mfma_f32_16x16x32_bf16(af[i], bfv[j], acc[i][j], 0,0,0);
  }
  #pragma unroll
  for (int i=0;i<4;++i){
    #pragma unroll
    for (int j=0;j<4;++j){
      const int col = bn*128 + wc*64 + j*16 + l15;
      float bv;
      if constexpr (MODE==2) bv = 0.f; else bv = bias[col];
      #pragma unroll
      for (int r=0;r<4;++r){
        const int row = bm*128 + wr*64 + i*16 + lg*4 + r;
        float v = acc[i][j][r] + bv;
        if constexpr (MODE==0){
          const int b_ = row >> 11, s_ = row & 2047;
          if (col < 1024){
            const int h = col>>6, d = col&63;
            qO[((size_t)(b_*16+h)*2048 + s_)*64 + d] = (__bf16)v;
          } else if (col < 2048){
            const int h = (col-1024)>>6, d = (col-1024)&63;
            kO[((size_t)(b_*16+h)*2048 + s_)*64 + d] = (__bf16)v;
          } else {
            const int h = (col-2048)>>6, d = (col-2048)&63;
            vtO[((size_t)(b_*16+h)*64 + d)*2048 + s_] = (__bf16)v;
          }
        } else if constexpr (MODE==1){
          outF[(size_t)row*N + col] = v + resid[(size_t)row*N + col];
        } else {
          const float gl = 0.5f*v*(1.f + erff(v*0.70710678118f));
          outB[(size_t)row*N + col] = (__bf16)gl;
        }
      }
    }
  }
}

// ---------------- flash attention v5, causal. KVBLK=128.
// Block: 512 threads / 8 waves, 128 q-rows (16/wave). Double-buffered LDS,
// stage-before-compute, swapped QK^T (lane owns one q-row -> in-lane softmax).
// Q,K: [bh][s][64] bf16 ; Vt: [bh][64][s] bf16 ; out: [b*2048+s][h*64+d] bf16
__global__ __launch_bounds__(512, 4) void attn_kernel(
    const __bf16* __restrict__ Q, const __bf16* __restrict__ K,
    const __bf16* __restrict__ Vt, __bf16* __restrict__ out)
{
  __shared__ __align__(16) __bf16 Ks[2][128*64];    // [kv 128][d 64] swizzled
  __shared__ __align__(16) __bf16 Vs[2][2][64*64];  // [kvhalf][d 64][kv 64] swizzled
  __shared__ __align__(16) __bf16 Pl[8][16*64];
  const int tid = threadIdx.x;
  const int lane = tid & 63, wave = tid >> 6;
  const int l15 = lane & 15, lg = lane >> 4;
  const int bh = blockIdx.y;
  const int qblk = (int)(gridDim.x - 1) - blockIdx.x;   // longest blocks first
  const int qb = qblk * 128;
  const int qw = qb + wave*16;                          // wave's first q-row
  const __bf16* Qh = Q + (size_t)bh*2048*64;
  const char*  Khc = (const char*)(K  + (size_t)bh*2048*64);
  const char*  Vhc = (const char*)(Vt + (size_t)bh*64*2048);

  bf16x8 qf[2];
  #pragma unroll
  for (int f=0;f<2;++f){
    bf16x8 t8 = *(const bf16x8*)&Qh[(size_t)(qw + l15)*64 + f*32 + lg*8];
    #pragma unroll
    for (int j=0;j<8;++j) t8[j] = (__bf16)((float)t8[j] * 0.125f);
    qf[f] = t8;
  }

  f32x4 oacc[4] = {};
  float mrun = -1e30f, lrun = 0.f;

  const int swz_st = (((lane&7) ^ (lane>>3)) << 4);     // staging source swizzle
  const int rswz = ((l15 & 7) << 4);                    // read-side swizzle (row%8 == l15%8)
  char* Pw = (char*)&Pl[wave][0];

  // staging assignments
  const int krow = wave*16 + (lane>>3);                 // K rows: wave covers [wave*16, +16)
  const int kh   = wave & 1;                            // V subtile (kv half)
  const int dgrp = wave >> 1;                           // V d-row group
  const int vrow = dgrp*16 + (lane>>3);

  const int nst = qblk + 1;

  // prologue: stage tile 0 into buffer 0
  {
    gld_lds16(Khc + (size_t)krow*128 + swz_st,     (char*)&Ks[0][0] + wave*2048);
    gld_lds16(Khc + (size_t)(krow+8)*128 + swz_st, (char*)&Ks[0][0] + wave*2048 + 1024);
    const char* s = Vhc + kh*128 + swz_st;
    gld_lds16(s + (size_t)vrow*4096,     (char*)&Vs[0][kh][0] + dgrp*2048);
    gld_lds16(s + (size_t)(vrow+8)*4096, (char*)&Vs[0][kh][0] + dgrp*2048 + 1024);
  }
  __syncthreads();

  for (int st = 0; st < nst; ++st){
    const int cur = st & 1;
    const int kv0 = st*128;
    if (st+1 < nst){
      const size_t nkv0 = (size_t)(kv0 + 128);
      gld_lds16(Khc + (nkv0 + krow)*128 + swz_st,     (char*)&Ks[cur^1][0] + wave*2048);
      gld_lds16(Khc + (nkv0 + krow + 8)*128 + swz_st, (char*)&Ks[cur^1][0] + wave*2048 + 1024);
      const char* s = Vhc + nkv0*2 + kh*128 + swz_st;
      gld_lds16(s + (size_t)vrow*4096,     (char*)&Vs[cur^1][kh][0] + dgrp*2048);
      gld_lds16(s + (size_t)(vrow+8)*4096, (char*)&Vs[cur^1][kh][0] + dgrp*2048 + 1024);
    }
    if (kv0 <= qw + 15){
      const char* Kb = (const char*)&Ks[cur][0];
      // QK^T swapped: sc[t][r] = score(k = kv0+t*16+lg*4+r, q = qw+l15), pre-scaled
      f32x4 sc[8];
      #pragma unroll
      for (int t=0;t<8;++t) sc[t] = f32x4{0.f,0.f,0.f,0.f};
      #pragma unroll
      for (int t=0;t<8;++t){
        const int row = t*16 + l15;
        bf16x8 k0 = *(const bf16x8*)(Kb + row*128 + ((lg*16)      ^ rswz));
        bf16x8 k1 = *(const bf16x8*)(Kb + row*128 + ((64 + lg*16) ^ rswz));
        sc[t] = __builtin_amdgcn_mfma_f32_16x16x32_bf16(k0, qf[0], sc[t], 0,0,0);
        sc[t] = __builtin_amdgcn_mfma_f32_16x16x32_bf16(k1, qf[1], sc[t], 0,0,0);
      }
      // causal mask (diagonal step only)
      if (kv0 + 127 > qw){
        const int q = qw + l15;
        #pragma unroll
        for (int t=0;t<8;++t)
          #pragma unroll
          for (int r=0;r<4;++r)
            if (kv0 + t*16 + lg*4 + r > q) sc[t][r] = -1e30f;
      }
      // in-lane softmax over 32 regs + 2 shuffles across lg groups
      f32x4 mm;
      #pragma unroll
      for (int r=0;r<4;++r){
        float a = fmaxf(fmaxf(sc[0][r],sc[1][r]), fmaxf(sc[2][r],sc[3][r]));
        float b = fmaxf(fmaxf(sc[4][r],sc[5][r]), fmaxf(sc[6][r],sc[7][r]));
        mm[r] = fmaxf(a,b);
      }
      float mx = fmaxf(fmaxf(mm[0],mm[1]), fmaxf(mm[2],mm[3]));
      mx = fmaxf(mx, __shfl_xor(mx, 16));
      mx = fmaxf(mx, __shfl_xor(mx, 32));
      const float nm = fmaxf(mrun, mx);
      const float co = exp2f((mrun - nm) * 1.44269504f);
      #pragma unroll
      for (int t=0;t<8;++t)
        #pragma unroll
        for (int r=0;r<4;++r)
          sc[t][r] = exp2f((sc[t][r] - nm) * 1.44269504f);
      f32x4 ss;
      #pragma unroll
      for (int r=0;r<4;++r){
        float a = (sc[0][r]+sc[1][r]) + (sc[2][r]+sc[3][r]);
        float b = (sc[4][r]+sc[5][r]) + (sc[6][r]+sc[7][r]);
        ss[r] = a + b;
      }
      float rs = (ss[0]+ss[1]) + (ss[2]+ss[3]);
      rs += __shfl_xor(rs, 16);
      rs += __shfl_xor(rs, 32);
      lrun = lrun*co + rs;
      mrun = nm;
      float cor[4];
      #pragma unroll
      for (int r=0;r<4;++r) cor[r] = __shfl(co, lg*4+r);
      #pragma unroll
      for (int c=0;c<4;++c)
        #pragma unroll
        for (int r=0;r<4;++r)
          oacc[c][r] *= cor[r];
      // two kv-halves: P (16x64) -> LDS -> PV against V subtile
      #pragma unroll
      for (int h=0; h<2; ++h){
        #pragma unroll
        for (int t=0;t<4;++t){
          union { __bf16 hh[4]; uint2 u; } pk4;
          pk4.hh[0] = (__bf16)sc[h*4+t][0];
          pk4.hh[1] = (__bf16)sc[h*4+t][1];
          pk4.hh[2] = (__bf16)sc[h*4+t][2];
          pk4.hh[3] = (__bf16)sc[h*4+t][3];
          *(uint2*)(Pw + l15*128 + ((t*32 + lg*8) ^ rswz)) = pk4.u;
        }
        const char* Vb = (const char*)&Vs[cur][h][0];
        #pragma unroll
        for (int f=0;f<2;++f){
          bf16x8 pa = *(const bf16x8*)(Pw + l15*128 + ((f*64 + lg*16) ^ rswz));
          #pragma unroll
          for (int c=0;c<4;++c){
            bf16x8 vf = *(const bf16x8*)(Vb + (c*16+l15)*128 + ((f*64 + lg*16) ^ rswz));
            oacc[c] = __builtin_amdgcn_mfma_f32_16x16x32_bf16(pa, vf, oacc[c], 0,0,0);
          }
        }
      }
    }
    __syncthreads();   // drains vmcnt(0): next tile ready; all waves done with cur
  }

  const int b_ = bh >> 4, h_ = bh & 15;
  float lr[4];
  #pragma unroll
  for (int r=0;r<4;++r) lr[r] = __shfl(lrun, lg*4+r);
  #pragma unroll
  for (int c=0;c<4;++c)
    #pragma unroll
    for (int r=0;r<4;++r){
      const int row = qw + lg*4 + r;
      out[((size_t)(b_*2048 + row))*1024 + h_*64 + c*16 + l15] = (__bf16)(oacc[c][r] / lr[r]);
    }
}

extern "C" void kernel_launch(void* const* d_in, const int* in_sizes, int n_in,
                              void* d_out, int out_size, void* d_ws, size_t ws_size,
                              hipStream_t stream) {
  const float* x      = (const float*)d_in[0];
  const float* ln1_g  = (const float*)d_in[1];
  const float* ln1_b  = (const float*)d_in[2];
  const float* w_qkv  = (const float*)d_in[3];
  const float* b_qkv  = (const float*)d_in[4];
  const float* w_dense= (const float*)d_in[5];
  const float* b_dense= (const float*)d_in[6];
  const float* ln2_g  = (const float*)d_in[7];
  const float* ln2_b  = (const float*)d_in[8];
  const float* w_fc1  = (const float*)d_in[9];
  const float* w_fc2  = (const float*)d_in[10];
  const float* b_fc2  = (const float*)d_in[11];

  char* ws = (char*)d_ws;
  __bf16* wqkvT  = (__bf16*)(ws + 0);          // [3072][1024]  6 MB
  __bf16* wdenT  = (__bf16*)(ws + 6291456);    // [1024][1024]  2 MB
  __bf16* wfc1T  = (__bf16*)(ws + 8388608);    // [2048][1024]  4 MB
  __bf16* wfc2T  = (__bf16*)(ws + 12582912);   // [1024][2048]  4 MB
  __bf16* xn     = (__bf16*)(ws + 16777216);   // [4096][1024]  8 MB
  __bf16* Qb     = (__bf16*)(ws + 25165824);   // [32][2048][64] 8 MB
  __bf16* Kb     = (__bf16*)(ws + 33554432);   // [32][2048][64] 8 MB
  __bf16* Vtb    = (__bf16*)(ws + 41943040);   // [32][64][2048] 8 MB
  __bf16* attnb  = (__bf16*)(ws + 50331648);   // [4096][1024]  8 MB
  float*  outf   = (float*) (ws + 58720256);   // [4096][1024] 16 MB
  __bf16* mb     = (__bf16*)(ws + 75497472);   // [4096][1024]  8 MB
  __bf16* h1b    = (__bf16*)(ws + 83886080);   // [4096][2048] 16 MB

  transpose_all<<<8192, dim3(32,8), 0, stream>>>(w_qkv, w_dense, w_fc1, w_fc2,
                                                 wqkvT, wdenT, wfc1T, wfc2T);
  ln_kernel<<<4096, 256, 0, stream>>>(x, ln1_g, ln1_b, xn);
  gemm_bt<0><<<dim3(32,24), 256, 0, stream>>>(xn, wqkvT, b_qkv, nullptr,
                                              nullptr, nullptr, Qb, Kb, Vtb, 4096, 3072, 1024);
  attn_kernel<<<dim3(16,32), 512, 0, stream>>>(Qb, Kb, Vtb, attnb);
  gemm_bt<1><<<dim3(32,8), 256, 0, stream>>>(attnb, wdenT, b_dense, x,
                                             outf, nullptr, nullptr, nullptr, nullptr, 4096, 1024, 1024);
  ln_kernel<<<4096, 256, 0, stream>>>(outf, ln2_g, ln2_b, mb);
  gemm_bt<2><<<dim3(32,16), 256, 0, stream>>>(mb, wfc1T, nullptr, nullptr,
                                              nullptr, h1b, nullptr, nullptr, nullptr, 4096, 2048, 1024);
  gemm_bt<1><<<dim3(32,8), 256, 0, stream>>>(h1b, wfc2T, b_fc2, outf,
                                             (float*)d_out, nullptr, nullptr, nullptr, nullptr, 4096, 1024, 2048);
}

// Round 7
// 195.417 us; speedup vs baseline: 1.4908x; 1.2699x over previous
//
#include <hip/hip_runtime.h>
#include <hip/hip_bf16.h>

typedef __bf16 bf16x8 __attribute__((ext_vector_type(8)));
typedef float  f32x4  __attribute__((ext_vector_type(4)));

typedef __attribute__((address_space(3))) unsigned int as3_u32;
typedef __attribute__((address_space(1))) unsigned int as1_u32;

__device__ __forceinline__ void gld_lds16(const void* gptr, void* lptr){
  __builtin_amdgcn_global_load_lds((const as1_u32*)gptr, (as3_u32*)lptr, 16, 0, 0);
}

// ---------------- all-weight convert + transpose: in[R][C] f32 -> out[C][R] bf16 (one launch)
__global__ __launch_bounds__(256) void transpose_all(
    const float* __restrict__ w_qkv, const float* __restrict__ w_dense,
    const float* __restrict__ w_fc1, const float* __restrict__ w_fc2,
    __bf16* __restrict__ oqkv, __bf16* __restrict__ oden,
    __bf16* __restrict__ ofc1, __bf16* __restrict__ ofc2){
  __shared__ float tile[32][33];
  int idx = blockIdx.x;
  const float* in; __bf16* out; int R, C;
  if (idx < 3072){ in = w_qkv;  out = oqkv; R = 1024; C = 3072; }
  else if (idx < 4096){ idx -= 3072; in = w_dense; out = oden; R = 1024; C = 1024; }
  else if (idx < 6144){ idx -= 4096; in = w_fc1;  out = ofc1; R = 1024; C = 2048; }
  else { idx -= 6144; in = w_fc2;  out = ofc2; R = 2048; C = 1024; }
  const int ntx = C >> 5;
  const int c0 = (idx % ntx)*32, r0 = (idx / ntx)*32;
  const int tx = threadIdx.x, ty = threadIdx.y;
  #pragma unroll
  for (int i=0;i<32;i+=8)
    tile[ty+i][tx] = in[(size_t)(r0+ty+i)*C + c0+tx];
  __syncthreads();
  #pragma unroll
  for (int i=0;i<32;i+=8)
    out[(size_t)(c0+ty+i)*R + r0+tx] = (__bf16)tile[tx][ty+i];
}

// ---------------- layernorm: rows of 1024 f32 -> bf16
__global__ __launch_bounds__(256) void ln_kernel(const float* __restrict__ x, const float* __restrict__ g,
                                                 const float* __restrict__ b, __bf16* __restrict__ out){
  const int row = blockIdx.x, t = threadIdx.x;
  const float4 v = ((const float4*)(x + (size_t)row*1024))[t];
  float s = v.x+v.y+v.z+v.w;
  #pragma unroll
  for (int m=1;m<64;m<<=1) s += __shfl_xor(s, m);
  __shared__ float red[8];
  if ((t&63)==0) red[t>>6] = s;
  __syncthreads();
  const float mu = (red[0]+red[1]+red[2]+red[3]) * (1.f/1024.f);
  const float d0=v.x-mu, d1=v.y-mu, d2=v.z-mu, d3=v.w-mu;
  float sq = d0*d0+d1*d1+d2*d2+d3*d3;
  #pragma unroll
  for (int m=1;m<64;m<<=1) sq += __shfl_xor(sq, m);
  if ((t&63)==0) red[4+(t>>6)] = sq;
  __syncthreads();
  const float var = (red[4]+red[5]+red[6]+red[7]) * (1.f/1024.f);
  const float inv = rsqrtf(var + 1e-12f);
  const float4 gv = ((const float4*)g)[t];
  const float4 bv = ((const float4*)b)[t];
  union { __bf16 h[4]; uint2 u; } pk;
  pk.h[0]=(__bf16)(d0*inv*gv.x+bv.x); pk.h[1]=(__bf16)(d1*inv*gv.y+bv.y);
  pk.h[2]=(__bf16)(d2*inv*gv.z+bv.z); pk.h[3]=(__bf16)(d3*inv*gv.w+bv.w);
  *(uint2*)(out + (size_t)row*1024 + t*4) = pk.u;
}

// ---------------- GEMM (2-phase pipelined 128x128): C = A @ Bt^T + bias, fused epilogues
// T3-minimum: stage(next) BEFORE compute(cur), double-buffered LDS, one barrier per K-step.
// MODE 0: QKV scatter -> Q[bh][s][d], K[bh][s][d], Vt[bh][d][s]  (bf16)
// MODE 1: outF = C + bias + resid (fp32)
// MODE 2: outB = gelu_exact(C) (bf16), no bias
template<int MODE>
__global__ __launch_bounds__(256) void gemm_bt(
    const __bf16* __restrict__ A, const __bf16* __restrict__ Bt,
    const float* __restrict__ bias, const float* __restrict__ resid,
    float* __restrict__ outF, __bf16* __restrict__ outB,
    __bf16* __restrict__ qO, __bf16* __restrict__ kO, __bf16* __restrict__ vtO,
    int M, int N, int K)
{
  __shared__ __align__(16) __bf16 As[2][128*32];
  __shared__ __align__(16) __bf16 Bs[2][128*32];
  const int tid = threadIdx.x;
  const int lane = tid & 63, wave = tid >> 6;
  const int wr = wave >> 1, wc = wave & 1;
  const int l15 = lane & 15, lg = lane >> 4;
  const int bm = blockIdx.x, bn = blockIdx.y;
  const __bf16* Ab = A  + (size_t)bm*128*K;
  const __bf16* Bb = Bt + (size_t)bn*128*K;
  f32x4 acc[4][4] = {};
  const int r0 = tid >> 2;
  const int c0 = (tid & 3) * 8;

  auto stage = [&](int kt, int b){
    const int k0 = kt*32;
    char* dA = (char*)&As[b][0] + wave*1024;
    char* dB = (char*)&Bs[b][0] + wave*1024;
    gld_lds16(Ab + (size_t)r0*K      + k0 + c0, dA);
    gld_lds16(Ab + (size_t)(r0+64)*K + k0 + c0, dA + 4096);
    gld_lds16(Bb + (size_t)r0*K      + k0 + c0, dB);
    gld_lds16(Bb + (size_t)(r0+64)*K + k0 + c0, dB + 4096);
  };

  const int nk = K >> 5;
  stage(0, 0);
  __syncthreads();
  for (int kt = 0; kt < nk; ++kt){
    const int b = kt & 1;
    if (kt+1 < nk) stage(kt+1, b^1);     // issue next tile first: latency hides under compute
    bf16x8 af[4], bfv[4];
    #pragma unroll
    for (int i=0;i<4;++i){
      af[i]  = *(const bf16x8*)&As[b][(wr*64 + i*16 + l15)*32 + lg*8];
      bfv[i] = *(const bf16x8*)&Bs[b][(wc*64 + i*16 + l15)*32 + lg*8];
    }
    #pragma unroll
    for (int i=0;i<4;++i)
      #pragma unroll
      for (int j=0;j<4;++j)
        acc[i][j] = __builtin_amdgcn_mfma_f32_16x16x32_bf16(af[i], bfv[j], acc[i][j], 0,0,0);
    __syncthreads();                     // drains vmcnt(0): next buffer ready; cur readers done
  }
  #pragma unroll
  for (int i=0;i<4;++i){
    #pragma unroll
    for (int j=0;j<4;++j){
      const int col = bn*128 + wc*64 + j*16 + l15;
      float bv;
      if constexpr (MODE==2) bv = 0.f; else bv = bias[col];
      #pragma unroll
      for (int r=0;r<4;++r){
        const int row = bm*128 + wr*64 + i*16 + lg*4 + r;
        float v = acc[i][j][r] + bv;
        if constexpr (MODE==0){
          const int b_ = row >> 11, s_ = row & 2047;
          if (col < 1024){
            const int h = col>>6, d = col&63;
            qO[((size_t)(b_*16+h)*2048 + s_)*64 + d] = (__bf16)v;
          } else if (col < 2048){
            const int h = (col-1024)>>6, d = (col-1024)&63;
            kO[((size_t)(b_*16+h)*2048 + s_)*64 + d] = (__bf16)v;
          } else {
            const int h = (col-2048)>>6, d = (col-2048)&63;
            vtO[((size_t)(b_*16+h)*64 + d)*2048 + s_] = (__bf16)v;
          }
        } else if constexpr (MODE==1){
          outF[(size_t)row*N + col] = v + resid[(size_t)row*N + col];
        } else {
          const float gl = 0.5f*v*(1.f + erff(v*0.70710678118f));
          outB[(size_t)row*N + col] = (__bf16)gl;
        }
      }
    }
  }
}

// ---------------- flash attention v5, causal. KVBLK=128.
// Block: 512 threads / 8 waves, 128 q-rows (16/wave). Double-buffered LDS,
// stage-before-compute, swapped QK^T (lane owns one q-row -> in-lane softmax).
// Load-balanced qblk remap: co-resident pairs (y, y+16) get complementary work.
// Q,K: [bh][s][64] bf16 ; Vt: [bh][64][s] bf16 ; out: [b*2048+s][h*64+d] bf16
__global__ __launch_bounds__(512, 4) void attn_kernel(
    const __bf16* __restrict__ Q, const __bf16* __restrict__ K,
    const __bf16* __restrict__ Vt, __bf16* __restrict__ out)
{
  __shared__ __align__(16) __bf16 Ks[2][128*64];    // [kv 128][d 64] swizzled
  __shared__ __align__(16) __bf16 Vs[2][2][64*64];  // [kvhalf][d 64][kv 64] swizzled
  __shared__ __align__(16) __bf16 Pl[8][16*64];
  const int tid = threadIdx.x;
  const int lane = tid & 63, wave = tid >> 6;
  const int l15 = lane & 15, lg = lane >> 4;
  const int bh = blockIdx.y;
  // complementary work pairing: blocks (x, y) and (x, y+16) co-reside on a CU;
  // give them qblk x and 15-x so every CU does ~17 steps instead of 2..32.
  const int nqb = (int)gridDim.x;
  const int qblk = (bh & 16) ? (int)blockIdx.x : (nqb - 1 - (int)blockIdx.x);
  const int qb = qblk * 128;
  const int qw = qb + wave*16;                          // wave's first q-row
  const __bf16* Qh = Q + (size_t)bh*2048*64;
  const char*  Khc = (const char*)(K  + (size_t)bh*2048*64);
  const char*  Vhc = (const char*)(Vt + (size_t)bh*64*2048);

  bf16x8 qf[2];
  #pragma unroll
  for (int f=0;f<2;++f){
    bf16x8 t8 = *(const bf16x8*)&Qh[(size_t)(qw + l15)*64 + f*32 + lg*8];
    #pragma unroll
    for (int j=0;j<8;++j) t8[j] = (__bf16)((float)t8[j] * 0.125f);
    qf[f] = t8;
  }

  f32x4 oacc[4] = {};
  float mrun = -1e30f, lrun = 0.f;

  const int swz_st = (((lane&7) ^ (lane>>3)) << 4);     // staging source swizzle
  const int rswz = ((l15 & 7) << 4);                    // read-side swizzle (row%8 == l15%8)
  char* Pw = (char*)&Pl[wave][0];

  // staging assignments
  const int krow = wave*16 + (lane>>3);                 // K rows: wave covers [wave*16, +16)
  const int kh   = wave & 1;                            // V subtile (kv half)
  const int dgrp = wave >> 1;                           // V d-row group
  const int vrow = dgrp*16 + (lane>>3);

  const int nst = qblk + 1;

  // prologue: stage tile 0 into buffer 0
  {
    gld_lds16(Khc + (size_t)krow*128 + swz_st,     (char*)&Ks[0][0] + wave*2048);
    gld_lds16(Khc + (size_t)(krow+8)*128 + swz_st, (char*)&Ks[0][0] + wave*2048 + 1024);
    const char* s = Vhc + kh*128 + swz_st;
    gld_lds16(s + (size_t)vrow*4096,     (char*)&Vs[0][kh][0] + dgrp*2048);
    gld_lds16(s + (size_t)(vrow+8)*4096, (char*)&Vs[0][kh][0] + dgrp*2048 + 1024);
  }
  __syncthreads();

  for (int st = 0; st < nst; ++st){
    const int cur = st & 1;
    const int kv0 = st*128;
    if (st+1 < nst){
      const size_t nkv0 = (size_t)(kv0 + 128);
      gld_lds16(Khc + (nkv0 + krow)*128 + swz_st,     (char*)&Ks[cur^1][0] + wave*2048);
      gld_lds16(Khc + (nkv0 + krow + 8)*128 + swz_st, (char*)&Ks[cur^1][0] + wave*2048 + 1024);
      const char* s = Vhc + nkv0*2 + kh*128 + swz_st;
      gld_lds16(s + (size_t)vrow*4096,     (char*)&Vs[cur^1][kh][0] + dgrp*2048);
      gld_lds16(s + (size_t)(vrow+8)*4096, (char*)&Vs[cur^1][kh][0] + dgrp*2048 + 1024);
    }
    if (kv0 <= qw + 15){
      const char* Kb = (const char*)&Ks[cur][0];
      // QK^T swapped: sc[t][r] = score(k = kv0+t*16+lg*4+r, q = qw+l15), pre-scaled
      f32x4 sc[8];
      #pragma unroll
      for (int t=0;t<8;++t) sc[t] = f32x4{0.f,0.f,0.f,0.f};
      #pragma unroll
      for (int t=0;t<8;++t){
        const int row = t*16 + l15;
        bf16x8 k0 = *(const bf16x8*)(Kb + row*128 + ((lg*16)      ^ rswz));
        bf16x8 k1 = *(const bf16x8*)(Kb + row*128 + ((64 + lg*16) ^ rswz));
        sc[t] = __builtin_amdgcn_mfma_f32_16x16x32_bf16(k0, qf[0], sc[t], 0,0,0);
        sc[t] = __builtin_amdgcn_mfma_f32_16x16x32_bf16(k1, qf[1], sc[t], 0,0,0);
      }
      // causal mask (diagonal step only)
      if (kv0 + 127 > qw){
        const int q = qw + l15;
        #pragma unroll
        for (int t=0;t<8;++t)
          #pragma unroll
          for (int r=0;r<4;++r)
            if (kv0 + t*16 + lg*4 + r > q) sc[t][r] = -1e30f;
      }
      // in-lane softmax over 32 regs + 2 shuffles across lg groups
      f32x4 mm;
      #pragma unroll
      for (int r=0;r<4;++r){
        float a = fmaxf(fmaxf(sc[0][r],sc[1][r]), fmaxf(sc[2][r],sc[3][r]));
        float b = fmaxf(fmaxf(sc[4][r],sc[5][r]), fmaxf(sc[6][r],sc[7][r]));
        mm[r] = fmaxf(a,b);
      }
      float mx = fmaxf(fmaxf(mm[0],mm[1]), fmaxf(mm[2],mm[3]));
      mx = fmaxf(mx, __shfl_xor(mx, 16));
      mx = fmaxf(mx, __shfl_xor(mx, 32));
      const float nm = fmaxf(mrun, mx);
      const float co = exp2f((mrun - nm) * 1.44269504f);
      #pragma unroll
      for (int t=0;t<8;++t)
        #pragma unroll
        for (int r=0;r<4;++r)
          sc[t][r] = exp2f((sc[t][r] - nm) * 1.44269504f);
      f32x4 ss;
      #pragma unroll
      for (int r=0;r<4;++r){
        float a = (sc[0][r]+sc[1][r]) + (sc[2][r]+sc[3][r]);
        float b = (sc[4][r]+sc[5][r]) + (sc[6][r]+sc[7][r]);
        ss[r] = a + b;
      }
      float rs = (ss[0]+ss[1]) + (ss[2]+ss[3]);
      rs += __shfl_xor(rs, 16);
      rs += __shfl_xor(rs, 32);
      lrun = lrun*co + rs;
      mrun = nm;
      float cor[4];
      #pragma unroll
      for (int r=0;r<4;++r) cor[r] = __shfl(co, lg*4+r);
      #pragma unroll
      for (int c=0;c<4;++c)
        #pragma unroll
        for (int r=0;r<4;++r)
          oacc[c][r] *= cor[r];
      // two kv-halves: P (16x64) -> LDS -> PV against V subtile
      #pragma unroll
      for (int h=0; h<2; ++h){
        #pragma unroll
        for (int t=0;t<4;++t){
          union { __bf16 hh[4]; uint2 u; } pk4;
          pk4.hh[0] = (__bf16)sc[h*4+t][0];
          pk4.hh[1] = (__bf16)sc[h*4+t][1];
          pk4.hh[2] = (__bf16)sc[h*4+t][2];
          pk4.hh[3] = (__bf16)sc[h*4+t][3];
          *(uint2*)(Pw + l15*128 + ((t*32 + lg*8) ^ rswz)) = pk4.u;
        }
        const char* Vb = (const char*)&Vs[cur][h][0];
        #pragma unroll
        for (int f=0;f<2;++f){
          bf16x8 pa = *(const bf16x8*)(Pw + l15*128 + ((f*64 + lg*16) ^ rswz));
          #pragma unroll
          for (int c=0;c<4;++c){
            bf16x8 vf = *(const bf16x8*)(Vb + (c*16+l15)*128 + ((f*64 + lg*16) ^ rswz));
            oacc[c] = __builtin_amdgcn_mfma_f32_16x16x32_bf16(pa, vf, oacc[c], 0,0,0);
          }
        }
      }
    }
    __syncthreads();   // drains vmcnt(0): next tile ready; all waves done with cur
  }

  const int b_ = bh >> 4, h_ = bh & 15;
  float lr[4];
  #pragma unroll
  for (int r=0;r<4;++r) lr[r] = __shfl(lrun, lg*4+r);
  #pragma unroll
  for (int c=0;c<4;++c)
    #pragma unroll
    for (int r=0;r<4;++r){
      const int row = qw + lg*4 + r;
      out[((size_t)(b_*2048 + row))*1024 + h_*64 + c*16 + l15] = (__bf16)(oacc[c][r] / lr[r]);
    }
}

extern "C" void kernel_launch(void* const* d_in, const int* in_sizes, int n_in,
                              void* d_out, int out_size, void* d_ws, size_t ws_size,
                              hipStream_t stream) {
  const float* x      = (const float*)d_in[0];
  const float* ln1_g  = (const float*)d_in[1];
  const float* ln1_b  = (const float*)d_in[2];
  const float* w_qkv  = (const float*)d_in[3];
  const float* b_qkv  = (const float*)d_in[4];
  const float* w_dense= (const float*)d_in[5];
  const float* b_dense= (const float*)d_in[6];
  const float* ln2_g  = (const float*)d_in[7];
  const float* ln2_b  = (const float*)d_in[8];
  const float* w_fc1  = (const float*)d_in[9];
  const float* w_fc2  = (const float*)d_in[10];
  const float* b_fc2  = (const float*)d_in[11];

  char* ws = (char*)d_ws;
  __bf16* wqkvT  = (__bf16*)(ws + 0);          // [3072][1024]  6 MB
  __bf16* wdenT  = (__bf16*)(ws + 6291456);    // [1024][1024]  2 MB
  __bf16* wfc1T  = (__bf16*)(ws + 8388608);    // [2048][1024]  4 MB
  __bf16* wfc2T  = (__bf16*)(ws + 12582912);   // [1024][2048]  4 MB
  __bf16* xn     = (__bf16*)(ws + 16777216);   // [4096][1024]  8 MB
  __bf16* Qb     = (__bf16*)(ws + 25165824);   // [32][2048][64] 8 MB
  __bf16* Kb     = (__bf16*)(ws + 33554432);   // [32][2048][64] 8 MB
  __bf16* Vtb    = (__bf16*)(ws + 41943040);   // [32][64][2048] 8 MB
  __bf16* attnb  = (__bf16*)(ws + 50331648);   // [4096][1024]  8 MB
  float*  outf   = (float*) (ws + 58720256);   // [4096][1024] 16 MB
  __bf16* mb     = (__bf16*)(ws + 75497472);   // [4096][1024]  8 MB
  __bf16* h1b    = (__bf16*)(ws + 83886080);   // [4096][2048] 16 MB

  transpose_all<<<8192, dim3(32,8), 0, stream>>>(w_qkv, w_dense, w_fc1, w_fc2,
                                                 wqkvT, wdenT, wfc1T, wfc2T);
  ln_kernel<<<4096, 256, 0, stream>>>(x, ln1_g, ln1_b, xn);
  gemm_bt<0><<<dim3(32,24), 256, 0, stream>>>(xn, wqkvT, b_qkv, nullptr,
                                              nullptr, nullptr, Qb, Kb, Vtb, 4096, 3072, 1024);
  attn_kernel<<<dim3(16,32), 512, 0, stream>>>(Qb, Kb, Vtb, attnb);
  gemm_bt<1><<<dim3(32,8), 256, 0, stream>>>(attnb, wdenT, b_dense, x,
                                             outf, nullptr, nullptr, nullptr, nullptr, 4096, 1024, 1024);
  ln_kernel<<<4096, 256, 0, stream>>>(outf, ln2_g, ln2_b, mb);
  gemm_bt<2><<<dim3(32,16), 256, 0, stream>>>(mb, wfc1T, nullptr, nullptr,
                                              nullptr, h1b, nullptr, nullptr, nullptr, 4096, 2048, 1024);
  gemm_bt<1><<<dim3(32,8), 256, 0, stream>>>(h1b, wfc2T, b_fc2, outf,
                                             (float*)d_out, nullptr, nullptr, nullptr, nullptr, 4096, 1024, 2048);
}